// Round 14
// baseline (254.247 us; speedup 1.0000x reference)
//
#include <hip/hip_runtime.h>
#include <cstdint>
#include <cstddef>
#include <math.h>

#define BN_   4
#define CC    96
#define C2    192
#define NN    3136
#define KNN   9
#define TILE  64
#define PT    8
#define WTS   100   /* transposed-weight LDS row stride: %4==0 (16B-aligned float4 rows) */
#define YSS   100   /* ys row stride: %4==0, breaks the stride-96 all-lanes-one-bank case */

typedef __attribute__((ext_vector_type(8))) __bf16 bf16x8;
typedef __attribute__((ext_vector_type(4))) float f32x4;

__device__ __forceinline__ unsigned short f2bf(float f) {
  unsigned int u = __float_as_uint(f);
  unsigned int r = u + 0x7fffu + ((u >> 16) & 1u);   // RNE
  return (unsigned short)(r >> 16);
}
__device__ __forceinline__ float bf2f(unsigned short h) {
  return __uint_as_float(((unsigned int)h) << 16);
}
// monotone map: fmono(a) > fmono(b)  <=>  a > b  (as floats)
__device__ __forceinline__ unsigned int fmono(float f) {
  unsigned int s = __float_as_uint(f);
  return s ^ ((unsigned int)((int)s >> 31) | 0x80000000u);
}

// top-9 of u64 keys kept as a SORTED-DESCENDING list; insert-by-shift.
// key = (fmono(v)<<32) | ~idx  => value desc, idx asc (jax top_k tie-break).
// Keys are unique (col in low bits); real keys are always > 0; init = all 0.
// NOTE (r4 post-mortem): a branchless f32-value + parallel-col variant of
// this body compiled to ~5x the VALU instructions (108us -> 428us).  Keep
// the u64 single-array guarded form -- it is the measured-best codegen.
__device__ __forceinline__ void topk_ins(uint64_t key, uint64_t (&bk)[KNN]) {
  if (key > bk[KNN - 1]) {
    #pragma unroll
    for (int j = KNN - 1; j >= 1; --j) {
      bool aj   = bk[j]     > key;
      bool ajm1 = bk[j - 1] > key;
      bk[j] = aj ? bk[j] : (ajm1 ? key : bk[j - 1]);  // uses ORIGINAL bk[j-1]
    }
    bk[0] = (bk[0] > key) ? bk[0] : key;
  }
}

// ---------------------------------------------------------------------------
// K1 (mega-fused, 512 threads -- r13 verified win): per position p
//   y  = bn1(fc1_w @ x + fc1_b)              (kept in LDS ys)
//   norm/bf16-split -> xh, xl, sq            (verbatim k_norm body, from LDS)
//   ymax[p][0:96]  = bnrelu(gcW[0:96] . y_blk)   (k-free gconv half)
//   zbuf[p][0:96]  = gcW[96:192] . y_blk         (k-dep gconv linearized)
// r10/r11 rule #20: xv[48] dot loops MUST be fully unrolled (partial unroll
// -> runtime index -> scratch -> 86MB writes, 114us).
// ---------------------------------------------------------------------------
__global__ __launch_bounds__(512) void k_fc1(const float* __restrict__ x,
                                             const float* __restrict__ w,
                                             const float* __restrict__ bias,
                                             const float* __restrict__ bn,
                                             const float* __restrict__ gcw,
                                             const float* __restrict__ gcb,
                                             const float* __restrict__ bng,
                                             float* __restrict__ ymax,
                                             float* __restrict__ zbuf,
                                             unsigned short* __restrict__ xh,
                                             unsigned short* __restrict__ xl,
                                             float* __restrict__ sq) {
  __shared__ float xs[CC * 64];                 // 24.0 KB [c][64]
  __shared__ float wT[CC * WTS];                // 38.4 KB wT[c*WTS + o]
  __shared__ __align__(16) float ys[64 * YSS];  // 25.6 KB [nn][c] (pad 100)
  __shared__ __align__(16) float gwl[C2 * 48];  // 36.9 KB gc weights
  __shared__ float bngL[5 * C2];                // 3.8 KB  4 bn rows + gc_b
  const int b = blockIdx.y, n0 = blockIdx.x * 64;
  const int t = threadIdx.x;
  for (int i = t; i < CC * 64; i += 512) {
    int c = i >> 6, nn = i & 63;
    xs[i] = x[((size_t)b * CC + c) * NN + n0 + nn];
  }
  for (int i = t; i < CC * CC; i += 512) {
    int o = i / CC, c = i % CC;        // w[o][c] row-major in global
    wT[c * WTS + o] = w[i];
  }
  for (int i = t; i < C2 * 48; i += 512) gwl[i] = gcw[i];
  for (int i = t; i < 4 * C2; i += 512) bngL[i] = bng[i];
  if (t < C2) bngL[4 * C2 + t] = gcb[t];
  __syncthreads();
  const int nn = t & 63;
  const int og = __builtin_amdgcn_readfirstlane(t >> 6);   // 0..7
  float acc[12];
  #pragma unroll
  for (int i = 0; i < 12; ++i) acc[i] = 0.f;
  for (int c = 0; c < CC; ++c) {
    float xv = xs[c * 64 + nn];
    const float* wp = &wT[c * WTS + og * 12];   // 16B-aligned broadcast
    float4 w0 = *(const float4*)(wp);
    float4 w1 = *(const float4*)(wp + 4);
    float4 w2 = *(const float4*)(wp + 8);
    const float wv[12] = {w0.x, w0.y, w0.z, w0.w, w1.x, w1.y, w1.z, w1.w,
                          w2.x, w2.y, w2.z, w2.w};
    #pragma unroll
    for (int oi = 0; oi < 12; ++oi) acc[oi] = fmaf(wv[oi], xv, acc[oi]);
  }
  #pragma unroll
  for (int oi = 0; oi < 12; ++oi) {
    int o = og * 12 + oi;
    float g = bn[o], be = bn[CC + o], mn = bn[2 * CC + o], vr = bn[3 * CC + o];
    float inv = g / sqrtf(vr + 1e-5f);
    float v = fmaf(acc[oi] + bias[o], inv, be - mn * inv);
    ys[nn * YSS + o] = v;
  }
  __syncthreads();

  // --- gconv k-free half + z precompute (8 waves: 24 outputs x 48-dot) ---
  {
    const int sel = og >> 2;                    // 0: ymax k-free, 1: z
    const int gg  = og & 3;                     // sub-wave within half
    const int cb  = (gg >> 1) * 48;             // input channel block
    const float* yrow = &ys[nn * YSS + cb];     // 16B-aligned
    float xv[48];
    #pragma unroll
    for (int c4 = 0; c4 < 12; ++c4) {
      float4 v4 = *(const float4*)(yrow + c4 * 4);
      xv[c4 * 4 + 0] = v4.x; xv[c4 * 4 + 1] = v4.y;
      xv[c4 * 4 + 2] = v4.z; xv[c4 * 4 + 3] = v4.w;
    }
    const size_t pg = (size_t)b * NN + n0 + nn;
    if (sel == 0) { // k-free: oc = gg*24 .. +24  (cb = (oc/48)*48 preserved)
      for (int oi = 0; oi < 24; ++oi) {
        int oc = gg * 24 + oi;
        const float* wr = &gwl[oc * 48];        // wave-uniform broadcast
        float a = 0.f;
        #pragma unroll                          // FULL unroll: xv[] stays in VGPRs
        for (int c = 0; c < 48; ++c) a = fmaf(wr[c], xv[c], a);
        float g = bngL[oc], be = bngL[C2 + oc], mn = bngL[2 * C2 + oc],
              vr = bngL[3 * C2 + oc], bs = bngL[4 * C2 + oc];
        float inv = g / sqrtf(vr + 1e-5f);
        ymax[pg * C2 + oc] = fmaxf(fmaf(a + bs, inv, be - mn * inv), 0.f);
      }
    } else {        // z: zoc = gg*24 .. +24, raw (no bias/bn)
      for (int oi = 0; oi < 24; ++oi) {
        int zoc = gg * 24 + oi;
        const float* wr = &gwl[(96 + zoc) * 48];
        float a = 0.f;
        #pragma unroll                          // FULL unroll: xv[] stays in VGPRs
        for (int c = 0; c < 48; ++c) a = fmaf(wr[c], xv[c], a);
        zbuf[pg * CC + zoc] = a;
      }
    }
  }

  // --- fused norm (verbatim old k_norm body, reading the LDS row) ---
  if (t < 64) {
    const size_t p = (size_t)b * NN + n0 + t;
    const float* row = &ys[t * YSS];            // 400B rows
    float s = 0.f;
    #pragma unroll
    for (int c = 0; c < CC; c += 4) {
      float4 v = *(const float4*)(row + c);
      s += v.x * v.x; s += v.y * v.y; s += v.z * v.z; s += v.w * v.w;
    }
    float inv = 1.f / fmaxf(sqrtf(s), 1e-12f);
    float sqs = 0.f;
    unsigned short* hrow = xh + p * CC;
    unsigned short* lrow = xl + p * CC;
    #pragma unroll
    for (int c = 0; c < CC; c += 4) {
      float4 v4 = *(const float4*)(row + c);
      float v0 = v4.x * inv, v1 = v4.y * inv, v2 = v4.z * inv, v3 = v4.w * inv;
      sqs += v0 * v0; sqs += v1 * v1; sqs += v2 * v2; sqs += v3 * v3;
      unsigned short h0 = f2bf(v0), h1 = f2bf(v1), h2 = f2bf(v2), h3 = f2bf(v3);
      float l0 = v0 - bf2f(h0), l1 = v1 - bf2f(h1), l2 = v2 - bf2f(h2), l3 = v3 - bf2f(h3);
      uint2 hv, lv;
      hv.x = (unsigned int)h0 | ((unsigned int)h1 << 16);
      hv.y = (unsigned int)h2 | ((unsigned int)h3 << 16);
      lv.x = (unsigned int)f2bf(l0) | ((unsigned int)f2bf(l1) << 16);
      lv.y = (unsigned int)f2bf(l2) | ((unsigned int)f2bf(l3) << 16);
      *(uint2*)&hrow[c] = hv;
      *(uint2*)&lrow[c] = lv;
    }
    sq[p] = sqs;
  }
}

// ---------------------------------------------------------------------------
// K3: Gram via bf16-split MFMA, swapped operands (D-col = our Gram row).
// r5-EXACT body.  FROZEN: r4 (branchless insert), r7 (staging decomp), r12
// (TM=32 tile) all regressed; occupancy cap (~44%) is NOT LDS-bound (r12).
// VALU-issue floor analysis: ~75us structural minimum at this body.
// ---------------------------------------------------------------------------
__global__ __launch_bounds__(256) void k_dist(const unsigned short* __restrict__ xh,
                                              const unsigned short* __restrict__ xl,
                                              const float* __restrict__ sq,
                                              uint64_t* __restrict__ cand_k) {
  __shared__ __align__(16) unsigned short sB[2 * 64 * 104];  // 26624 B
  __shared__ __align__(16) float sqm[TILE];
  unsigned short* BsH = sB;
  unsigned short* BsL = sB + 64 * 104;

  const int rt = blockIdx.x, chunk = blockIdx.y, b = blockIdx.z;
  const int nch = gridDim.y;
  const int r0 = rt * TILE;
  const int t = threadIdx.x;
  const int lane = t & 63, w = t >> 6;
  const int m16 = lane & 15, quad = lane >> 4;
  const int mt0 = (49 * chunk) / nch, mt1 = (49 * (chunk + 1)) / nch;

  // This lane's Gram row; A-fragments straight from global (once per block).
  const int gr = r0 + w * 16 + m16;
  bf16x8 ah[3], al[3];
  {
    const unsigned short* pH = xh + ((size_t)b * NN + gr) * CC + quad * 8;
    const unsigned short* pL = xl + ((size_t)b * NN + gr) * CC + quad * 8;
    #pragma unroll
    for (int kc = 0; kc < 3; ++kc) {
      ah[kc] = *(const bf16x8*)(pH + kc * 32);
      al[kc] = *(const bf16x8*)(pL + kc * 32);
    }
  }
  const float sr = sq[b * NN + gr];

  uint64_t bk[KNN];
  #pragma unroll
  for (int j = 0; j < KNN; ++j) bk[j] = 0ull;

  for (int mt = mt0; mt < mt1; ++mt) {
    const int m0 = mt * TILE;
    __syncthreads();  // prior tile's B-frag reads done before overwrite
    for (int i = t; i < 64 * 12; i += 256) {
      int r = i / 12, ch = i % 12;
      const uint4* sH = (const uint4*)(xh + ((size_t)b * NN + m0 + r) * CC);
      const uint4* sL = (const uint4*)(xl + ((size_t)b * NN + m0 + r) * CC);
      *(uint4*)&BsH[r * 104 + ch * 8] = sH[ch];
      *(uint4*)&BsL[r * 104 + ch * 8] = sL[ch];
    }
    if (t < TILE) sqm[t] = sq[b * NN + m0 + t];
    __syncthreads();

    #pragma unroll
    for (int tt = 0; tt < 4; ++tt) {
      const int brow = (tt * 16 + m16) * 104 + quad * 8;
      f32x4 acc = {0.f, 0.f, 0.f, 0.f};
      #pragma unroll
      for (int kc = 0; kc < 3; ++kc) {
        bf16x8 bh = *(const bf16x8*)&BsH[brow + kc * 32];
        bf16x8 bl = *(const bf16x8*)&BsL[brow + kc * 32];
        acc = __builtin_amdgcn_mfma_f32_16x16x32_bf16(bh, ah[kc], acc, 0, 0, 0);
        acc = __builtin_amdgcn_mfma_f32_16x16x32_bf16(bl, ah[kc], acc, 0, 0, 0);
        acc = __builtin_amdgcn_mfma_f32_16x16x32_bf16(bh, al[kc], acc, 0, 0, 0);
      }
      // lane's candidates: cols m0 + tt*16 + quad*4 + r, all for row gr
      float4 s4 = *(const float4*)&sqm[tt * 16 + quad * 4];  // broadcast read
      const float sv[4] = {s4.x, s4.y, s4.z, s4.w};
      #pragma unroll
      for (int r = 0; r < 4; ++r) {
        float v = 2.f * acc[r] - sr - sv[r];
        int col = m0 + tt * 16 + quad * 4 + r;
        uint64_t key = ((uint64_t)fmono(v) << 32) | (unsigned int)~col;
        topk_ins(key, bk);
      }
    }
  }
  __syncthreads();

  // merge the 4 per-quad lists of each row (scratch aliases sB)
  uint64_t* sk = (uint64_t*)sB;   // 64 rows * 4 quads * 9 * 8B = 18432 B
  #pragma unroll
  for (int j = 0; j < KNN; ++j) sk[((w * 16 + m16) * 4 + quad) * KNN + j] = bk[j];
  __syncthreads();
  if (t < TILE) {
    uint64_t fk[KNN];
    #pragma unroll
    for (int j = 0; j < KNN; ++j) fk[j] = 0ull;
    for (int qq = 0; qq < 4; ++qq)
      #pragma unroll
      for (int j = 0; j < KNN; ++j)
        topk_ins(sk[(t * 4 + qq) * KNN + j], fk);
    size_t base = (((size_t)b * nch + chunk) * NN + r0 + t) * KNN;
    #pragma unroll
    for (int j = 0; j < KNN; ++j) cand_k[base + j] = fk[j];
  }
}

// ---------------------------------------------------------------------------
// K5 (r14: nnmerge FUSED in): per block of PT=8 positions --
//   A) 32 threads: (p,q) each merge nch/4 chunk lists -> LDS skm
//   B) 8 threads: merge the 4 partials -> clamped idxl (u64 keys => tree
//      merge == sequential merge; ties resolved inside the key)
//   C) gather-max over linearized gconv: acc = z[jk] - z[i], bn-relu, max.
// Rationale: standalone k_nnmerge ran at 0.77 waves/SIMD (196 blocks) with a
// 72-insert serial chain; here the same work overlaps gmax's memory waits
// (1568 blocks, ~24 waves/CU) and one launch+gap+nnidx round-trip vanishes.
// ---------------------------------------------------------------------------
__global__ __launch_bounds__(256) void k_gmax(const float* __restrict__ zbuf,
                                              const uint64_t* __restrict__ cand_k,
                                              const float* __restrict__ gb,
                                              const float* __restrict__ bng,
                                              float* __restrict__ ymax, int nch) {
  __shared__ uint64_t skm[PT * 4 * KNN];   // 2304 B
  __shared__ int idxl[PT * KNN];
  const int t = threadIdx.x;
  const int p0 = blockIdx.x * PT;          // 3136 % PT == 0 => one batch/block
  const int b0 = p0 / NN;
  const int nl0 = p0 % NN;

  if (t < PT * 4) {                        // phase A
    const int p = t >> 2, q = t & 3;
    const int n = nl0 + p;
    const int cpw = nch >> 2;
    uint64_t fk[KNN];
    #pragma unroll
    for (int j = 0; j < KNN; ++j) fk[j] = 0ull;
    for (int ch = q * cpw; ch < (q + 1) * cpw; ++ch) {
      size_t base = (((size_t)b0 * nch + ch) * NN + n) * KNN;
      #pragma unroll
      for (int j = 0; j < KNN; ++j) topk_ins(cand_k[base + j], fk);
    }
    #pragma unroll
    for (int j = 0; j < KNN; ++j) skm[(p * 4 + q) * KNN + j] = fk[j];
  }
  __syncthreads();
  if (t < PT) {                            // phase B
    uint64_t gk[KNN];
    #pragma unroll
    for (int j = 0; j < KNN; ++j) gk[j] = 0ull;
    for (int q = 0; q < 4; ++q)
      #pragma unroll
      for (int j = 0; j < KNN; ++j)
        topk_ins(skm[(t * 4 + q) * KNN + j], gk);
    #pragma unroll
    for (int j = 0; j < KNN; ++j) {
      int v = (int)(~(unsigned int)gk[j]);
      if ((unsigned)v >= (unsigned)NN) v = 0;  // sentinel guard
      idxl[t * KNN + j] = v;
    }
  }
  __syncthreads();

  // phase C: gather-max (identical to r13's verified body)
  const int p = t >> 5, l = t & 31;
  const size_t pg = p0 + p;
  const float* zi = zbuf + pg * CC;
  const float* zb = zbuf + (size_t)b0 * NN * CC;
  const float zi0 = zi[l], zi1 = zi[l + 32], zi2 = zi[l + 64];
  const int o0 = 96 + l, o1 = o0 + 32, o2 = o0 + 64;
  const float inv0 = bng[o0] / sqrtf(bng[3 * C2 + o0] + 1e-5f);
  const float inv1 = bng[o1] / sqrtf(bng[3 * C2 + o1] + 1e-5f);
  const float inv2 = bng[o2] / sqrtf(bng[3 * C2 + o2] + 1e-5f);
  const float sh0 = bng[C2 + o0] - bng[2 * C2 + o0] * inv0;
  const float sh1 = bng[C2 + o1] - bng[2 * C2 + o1] * inv1;
  const float sh2 = bng[C2 + o2] - bng[2 * C2 + o2] * inv2;
  const float bs0 = gb[o0], bs1 = gb[o1], bs2 = gb[o2];
  float m0 = 0.f, m1 = 0.f, m2 = 0.f;
  #pragma unroll
  for (int k = 0; k < KNN; ++k) {
    const float* zj = zb + (size_t)idxl[p * KNN + k] * CC;
    float a0 = zj[l]      - zi0;
    float a1 = zj[l + 32] - zi1;
    float a2 = zj[l + 64] - zi2;
    m0 = fmaxf(m0, fmaxf(fmaf(a0 + bs0, inv0, sh0), 0.f));
    m1 = fmaxf(m1, fmaxf(fmaf(a1 + bs1, inv1, sh1), 0.f));
    m2 = fmaxf(m2, fmaxf(fmaf(a2 + bs2, inv2, sh2), 0.f));
  }
  float* orow = ymax + pg * C2 + 96;
  orow[l] = m0; orow[l + 32] = m1; orow[l + 64] = m2;
}

// ---------------------------------------------------------------------------
// K6: out = bn2(fc2_w @ ymax + fc2_b) + x.  512 threads (r13 verified win).
// w2 staged to LDS transposed (r6 win).  LDS = 126 KB.
// ---------------------------------------------------------------------------
__global__ __launch_bounds__(512) void k_fc2(const float* __restrict__ ymax,
                                             const float* __restrict__ w2,
                                             const float* __restrict__ b2,
                                             const float* __restrict__ bn2,
                                             const float* __restrict__ xin,
                                             float* __restrict__ out) {
  __shared__ float ys[64 * 193];       // 49.4 KB
  __shared__ float w2T[C2 * WTS];      // 76.8 KB, w2T[c2*WTS + o]
  const int b = blockIdx.y, n0 = blockIdx.x * 64, t = threadIdx.x;
  for (int i = t; i < 64 * C2; i += 512) {
    int nn = i / C2, c2 = i % C2;
    ys[nn * 193 + c2] = ymax[((size_t)b * NN + n0 + nn) * C2 + c2];
  }
  for (int i = t; i < CC * C2; i += 512) {
    int o = i / C2, c2 = i % C2;       // w2[o][c2] row-major in global
    w2T[c2 * WTS + o] = w2[i];
  }
  __syncthreads();
  const int nn = t & 63;
  const int og = __builtin_amdgcn_readfirstlane(t >> 6);   // 0..7
  float acc[12];
  #pragma unroll
  for (int i = 0; i < 12; ++i) acc[i] = 0.f;
  const float* yrow = ys + nn * 193;
  for (int c2 = 0; c2 < C2; ++c2) {
    float yv = yrow[c2];
    const float* wp = &w2T[c2 * WTS + og * 12];  // 16B-aligned
    float4 w0 = *(const float4*)(wp);
    float4 w1 = *(const float4*)(wp + 4);
    float4 w2v = *(const float4*)(wp + 8);
    const float wv[12] = {w0.x, w0.y, w0.z, w0.w, w1.x, w1.y, w1.z, w1.w,
                          w2v.x, w2v.y, w2v.z, w2v.w};
    #pragma unroll
    for (int oi = 0; oi < 12; ++oi) acc[oi] = fmaf(wv[oi], yv, acc[oi]);
  }
  #pragma unroll
  for (int oi = 0; oi < 12; ++oi) {
    int o = og * 12 + oi;
    float g = bn2[o], be = bn2[CC + o], mn = bn2[2 * CC + o], vr = bn2[3 * CC + o];
    float inv = g / sqrtf(vr + 1e-5f);
    float v = fmaf(acc[oi] + b2[o], inv, be - mn * inv);
    size_t off = ((size_t)b * CC + o) * NN + n0 + nn;
    out[off] = v + xin[off];
  }
}

// ---------------------------------------------------------------------------
extern "C" void kernel_launch(void* const* d_in, const int* in_sizes, int n_in,
                              void* d_out, int out_size, void* d_ws, size_t ws_size,
                              hipStream_t stream) {
  const float* x     = (const float*)d_in[0];
  const float* fc1_w = (const float*)d_in[1];
  const float* fc1_b = (const float*)d_in[2];
  const float* bn1   = (const float*)d_in[3];
  const float* gc_w  = (const float*)d_in[4];
  const float* gc_b  = (const float*)d_in[5];
  const float* bng   = (const float*)d_in[6];
  const float* fc2_w = (const float*)d_in[7];
  const float* fc2_b = (const float*)d_in[8];
  const float* bn2   = (const float*)d_in[9];
  float* out = (float*)d_out;

  const size_t BNC = (size_t)BN_ * NN * CC;
  float* ws = (float*)d_ws;
  float* zbuf = ws;                                   // B*N*96 fp32
  unsigned short* xh = (unsigned short*)(zbuf + BNC); // B*N*C bf16 hi
  unsigned short* xl = xh + BNC;                      // B*N*C bf16 lo
  float* sq     = ws + 2 * BNC;                       // B*N
  float* ymax   = sq + (size_t)BN_ * NN;              // B*N*C2 fp32
  // nn_idx buffer DELETED (merge fused into k_gmax); cand_k directly after
  // ymax.  nch ladder 16 -> 8 -> 4 by workspace (nch=4 = 24.3 MB, always
  // within the r0-verified budget).
  const size_t base_bytes =
      (2 * BNC + (size_t)BN_ * NN + (size_t)BN_ * NN * C2) * 4;
  uint64_t* cand_k = (uint64_t*)((char*)d_ws + base_bytes);
  int nch;
  if (ws_size >= base_bytes + (size_t)BN_ * 16 * NN * KNN * 8)      nch = 16;
  else if (ws_size >= base_bytes + (size_t)BN_ * 8 * NN * KNN * 8)  nch = 8;
  else                                                              nch = 4;

  k_fc1<<<dim3(NN / 64, BN_), 512, 0, stream>>>(x, fc1_w, fc1_b, bn1, gc_w,
                                                gc_b, bng, ymax, zbuf, xh, xl, sq);
  k_dist<<<dim3(NN / TILE, nch, BN_), 256, 0, stream>>>(xh, xl, sq, cand_k);
  k_gmax<<<dim3((BN_ * NN) / PT), 256, 0, stream>>>(zbuf, cand_k, gc_b, bng, ymax, nch);
  k_fc2<<<dim3(NN / 64, BN_), 512, 0, stream>>>(ymax, fc2_w, fc2_b, bn2, x, out);
}

// Round 15
// 241.089 us; speedup vs baseline: 1.0546x; 1.0546x over previous
//
#include <hip/hip_runtime.h>
#include <cstdint>
#include <cstddef>
#include <math.h>

#define BN_   4
#define CC    96
#define C2    192
#define NN    3136
#define KNN   9
#define TILE  64
#define PT    8
#define WTS   100   /* transposed-weight LDS row stride: %4==0 (16B-aligned float4 rows) */
#define YSS   100   /* ys row stride: %4==0, breaks the stride-96 all-lanes-one-bank case */

typedef __attribute__((ext_vector_type(8))) __bf16 bf16x8;
typedef __attribute__((ext_vector_type(4))) float f32x4;

__device__ __forceinline__ unsigned short f2bf(float f) {
  unsigned int u = __float_as_uint(f);
  unsigned int r = u + 0x7fffu + ((u >> 16) & 1u);   // RNE
  return (unsigned short)(r >> 16);
}
__device__ __forceinline__ float bf2f(unsigned short h) {
  return __uint_as_float(((unsigned int)h) << 16);
}
// monotone map: fmono(a) > fmono(b)  <=>  a > b  (as floats)
__device__ __forceinline__ unsigned int fmono(float f) {
  unsigned int s = __float_as_uint(f);
  return s ^ ((unsigned int)((int)s >> 31) | 0x80000000u);
}

// top-9 of u64 keys kept as a SORTED-DESCENDING list; insert-by-shift.
// key = (fmono(v)<<32) | ~idx  => value desc, idx asc (jax top_k tie-break).
// Keys are unique (col in low bits); real keys are always > 0; init = all 0.
// NOTE (r4 post-mortem): a branchless f32-value + parallel-col variant of
// this body compiled to ~5x the VALU instructions (108us -> 428us).  Keep
// the u64 single-array guarded form -- it is the measured-best codegen.
__device__ __forceinline__ void topk_ins(uint64_t key, uint64_t (&bk)[KNN]) {
  if (key > bk[KNN - 1]) {
    #pragma unroll
    for (int j = KNN - 1; j >= 1; --j) {
      bool aj   = bk[j]     > key;
      bool ajm1 = bk[j - 1] > key;
      bk[j] = aj ? bk[j] : (ajm1 ? key : bk[j - 1]);  // uses ORIGINAL bk[j-1]
    }
    bk[0] = (bk[0] > key) ? bk[0] : key;
  }
}

// ---------------------------------------------------------------------------
// K1 (mega-fused, 512 threads -- r13 verified win): per position p
//   y  = bn1(fc1_w @ x + fc1_b)              (kept in LDS ys)
//   norm/bf16-split -> xh, xl, sq            (verbatim k_norm body, from LDS)
//   ymax[p][0:96]  = bnrelu(gcW[0:96] . y_blk)   (k-free gconv half)
//   zbuf[p][0:96]  = gcW[96:192] . y_blk         (k-dep gconv linearized)
// r10/r11 rule #20: xv[48] dot loops MUST be fully unrolled (partial unroll
// -> runtime index -> scratch -> 86MB writes, 114us).
// ---------------------------------------------------------------------------
__global__ __launch_bounds__(512) void k_fc1(const float* __restrict__ x,
                                             const float* __restrict__ w,
                                             const float* __restrict__ bias,
                                             const float* __restrict__ bn,
                                             const float* __restrict__ gcw,
                                             const float* __restrict__ gcb,
                                             const float* __restrict__ bng,
                                             float* __restrict__ ymax,
                                             float* __restrict__ zbuf,
                                             unsigned short* __restrict__ xh,
                                             unsigned short* __restrict__ xl,
                                             float* __restrict__ sq) {
  __shared__ float xs[CC * 64];                 // 24.0 KB [c][64]
  __shared__ float wT[CC * WTS];                // 38.4 KB wT[c*WTS + o]
  __shared__ __align__(16) float ys[64 * YSS];  // 25.6 KB [nn][c] (pad 100)
  __shared__ __align__(16) float gwl[C2 * 48];  // 36.9 KB gc weights
  __shared__ float bngL[5 * C2];                // 3.8 KB  4 bn rows + gc_b
  const int b = blockIdx.y, n0 = blockIdx.x * 64;
  const int t = threadIdx.x;
  for (int i = t; i < CC * 64; i += 512) {
    int c = i >> 6, nn = i & 63;
    xs[i] = x[((size_t)b * CC + c) * NN + n0 + nn];
  }
  for (int i = t; i < CC * CC; i += 512) {
    int o = i / CC, c = i % CC;        // w[o][c] row-major in global
    wT[c * WTS + o] = w[i];
  }
  for (int i = t; i < C2 * 48; i += 512) gwl[i] = gcw[i];
  for (int i = t; i < 4 * C2; i += 512) bngL[i] = bng[i];
  if (t < C2) bngL[4 * C2 + t] = gcb[t];
  __syncthreads();
  const int nn = t & 63;
  const int og = __builtin_amdgcn_readfirstlane(t >> 6);   // 0..7
  float acc[12];
  #pragma unroll
  for (int i = 0; i < 12; ++i) acc[i] = 0.f;
  for (int c = 0; c < CC; ++c) {
    float xv = xs[c * 64 + nn];
    const float* wp = &wT[c * WTS + og * 12];   // 16B-aligned broadcast
    float4 w0 = *(const float4*)(wp);
    float4 w1 = *(const float4*)(wp + 4);
    float4 w2 = *(const float4*)(wp + 8);
    const float wv[12] = {w0.x, w0.y, w0.z, w0.w, w1.x, w1.y, w1.z, w1.w,
                          w2.x, w2.y, w2.z, w2.w};
    #pragma unroll
    for (int oi = 0; oi < 12; ++oi) acc[oi] = fmaf(wv[oi], xv, acc[oi]);
  }
  #pragma unroll
  for (int oi = 0; oi < 12; ++oi) {
    int o = og * 12 + oi;
    float g = bn[o], be = bn[CC + o], mn = bn[2 * CC + o], vr = bn[3 * CC + o];
    float inv = g / sqrtf(vr + 1e-5f);
    float v = fmaf(acc[oi] + bias[o], inv, be - mn * inv);
    ys[nn * YSS + o] = v;
  }
  __syncthreads();

  // --- gconv k-free half + z precompute (8 waves: 24 outputs x 48-dot) ---
  {
    const int sel = og >> 2;                    // 0: ymax k-free, 1: z
    const int gg  = og & 3;                     // sub-wave within half
    const int cb  = (gg >> 1) * 48;             // input channel block
    const float* yrow = &ys[nn * YSS + cb];     // 16B-aligned
    float xv[48];
    #pragma unroll
    for (int c4 = 0; c4 < 12; ++c4) {
      float4 v4 = *(const float4*)(yrow + c4 * 4);
      xv[c4 * 4 + 0] = v4.x; xv[c4 * 4 + 1] = v4.y;
      xv[c4 * 4 + 2] = v4.z; xv[c4 * 4 + 3] = v4.w;
    }
    const size_t pg = (size_t)b * NN + n0 + nn;
    if (sel == 0) { // k-free: oc = gg*24 .. +24  (cb = (oc/48)*48 preserved)
      for (int oi = 0; oi < 24; ++oi) {
        int oc = gg * 24 + oi;
        const float* wr = &gwl[oc * 48];        // wave-uniform broadcast
        float a = 0.f;
        #pragma unroll                          // FULL unroll: xv[] stays in VGPRs
        for (int c = 0; c < 48; ++c) a = fmaf(wr[c], xv[c], a);
        float g = bngL[oc], be = bngL[C2 + oc], mn = bngL[2 * C2 + oc],
              vr = bngL[3 * C2 + oc], bs = bngL[4 * C2 + oc];
        float inv = g / sqrtf(vr + 1e-5f);
        ymax[pg * C2 + oc] = fmaxf(fmaf(a + bs, inv, be - mn * inv), 0.f);
      }
    } else {        // z: zoc = gg*24 .. +24, raw (no bias/bn)
      for (int oi = 0; oi < 24; ++oi) {
        int zoc = gg * 24 + oi;
        const float* wr = &gwl[(96 + zoc) * 48];
        float a = 0.f;
        #pragma unroll                          // FULL unroll: xv[] stays in VGPRs
        for (int c = 0; c < 48; ++c) a = fmaf(wr[c], xv[c], a);
        zbuf[pg * CC + zoc] = a;
      }
    }
  }

  // --- fused norm (verbatim old k_norm body, reading the LDS row) ---
  if (t < 64) {
    const size_t p = (size_t)b * NN + n0 + t;
    const float* row = &ys[t * YSS];            // 400B rows
    float s = 0.f;
    #pragma unroll
    for (int c = 0; c < CC; c += 4) {
      float4 v = *(const float4*)(row + c);
      s += v.x * v.x; s += v.y * v.y; s += v.z * v.z; s += v.w * v.w;
    }
    float inv = 1.f / fmaxf(sqrtf(s), 1e-12f);
    float sqs = 0.f;
    unsigned short* hrow = xh + p * CC;
    unsigned short* lrow = xl + p * CC;
    #pragma unroll
    for (int c = 0; c < CC; c += 4) {
      float4 v4 = *(const float4*)(row + c);
      float v0 = v4.x * inv, v1 = v4.y * inv, v2 = v4.z * inv, v3 = v4.w * inv;
      sqs += v0 * v0; sqs += v1 * v1; sqs += v2 * v2; sqs += v3 * v3;
      unsigned short h0 = f2bf(v0), h1 = f2bf(v1), h2 = f2bf(v2), h3 = f2bf(v3);
      float l0 = v0 - bf2f(h0), l1 = v1 - bf2f(h1), l2 = v2 - bf2f(h2), l3 = v3 - bf2f(h3);
      uint2 hv, lv;
      hv.x = (unsigned int)h0 | ((unsigned int)h1 << 16);
      hv.y = (unsigned int)h2 | ((unsigned int)h3 << 16);
      lv.x = (unsigned int)f2bf(l0) | ((unsigned int)f2bf(l1) << 16);
      lv.y = (unsigned int)f2bf(l2) | ((unsigned int)f2bf(l3) << 16);
      *(uint2*)&hrow[c] = hv;
      *(uint2*)&lrow[c] = lv;
    }
    sq[p] = sqs;
  }
}

// ---------------------------------------------------------------------------
// K3: Gram via bf16-split MFMA, swapped operands (D-col = our Gram row).
// r5-EXACT body.  FROZEN: r4 (branchless insert), r7 (staging decomp), r12
// (TM=32 tile) all regressed; occupancy cap (~44%) is NOT LDS-bound (r12).
// ---------------------------------------------------------------------------
__global__ __launch_bounds__(256) void k_dist(const unsigned short* __restrict__ xh,
                                              const unsigned short* __restrict__ xl,
                                              const float* __restrict__ sq,
                                              uint64_t* __restrict__ cand_k) {
  __shared__ __align__(16) unsigned short sB[2 * 64 * 104];  // 26624 B
  __shared__ __align__(16) float sqm[TILE];
  unsigned short* BsH = sB;
  unsigned short* BsL = sB + 64 * 104;

  const int rt = blockIdx.x, chunk = blockIdx.y, b = blockIdx.z;
  const int nch = gridDim.y;
  const int r0 = rt * TILE;
  const int t = threadIdx.x;
  const int lane = t & 63, w = t >> 6;
  const int m16 = lane & 15, quad = lane >> 4;
  const int mt0 = (49 * chunk) / nch, mt1 = (49 * (chunk + 1)) / nch;

  // This lane's Gram row; A-fragments straight from global (once per block).
  const int gr = r0 + w * 16 + m16;
  bf16x8 ah[3], al[3];
  {
    const unsigned short* pH = xh + ((size_t)b * NN + gr) * CC + quad * 8;
    const unsigned short* pL = xl + ((size_t)b * NN + gr) * CC + quad * 8;
    #pragma unroll
    for (int kc = 0; kc < 3; ++kc) {
      ah[kc] = *(const bf16x8*)(pH + kc * 32);
      al[kc] = *(const bf16x8*)(pL + kc * 32);
    }
  }
  const float sr = sq[b * NN + gr];

  uint64_t bk[KNN];
  #pragma unroll
  for (int j = 0; j < KNN; ++j) bk[j] = 0ull;

  for (int mt = mt0; mt < mt1; ++mt) {
    const int m0 = mt * TILE;
    __syncthreads();  // prior tile's B-frag reads done before overwrite
    for (int i = t; i < 64 * 12; i += 256) {
      int r = i / 12, ch = i % 12;
      const uint4* sH = (const uint4*)(xh + ((size_t)b * NN + m0 + r) * CC);
      const uint4* sL = (const uint4*)(xl + ((size_t)b * NN + m0 + r) * CC);
      *(uint4*)&BsH[r * 104 + ch * 8] = sH[ch];
      *(uint4*)&BsL[r * 104 + ch * 8] = sL[ch];
    }
    if (t < TILE) sqm[t] = sq[b * NN + m0 + t];
    __syncthreads();

    #pragma unroll
    for (int tt = 0; tt < 4; ++tt) {
      const int brow = (tt * 16 + m16) * 104 + quad * 8;
      f32x4 acc = {0.f, 0.f, 0.f, 0.f};
      #pragma unroll
      for (int kc = 0; kc < 3; ++kc) {
        bf16x8 bh = *(const bf16x8*)&BsH[brow + kc * 32];
        bf16x8 bl = *(const bf16x8*)&BsL[brow + kc * 32];
        acc = __builtin_amdgcn_mfma_f32_16x16x32_bf16(bh, ah[kc], acc, 0, 0, 0);
        acc = __builtin_amdgcn_mfma_f32_16x16x32_bf16(bl, ah[kc], acc, 0, 0, 0);
        acc = __builtin_amdgcn_mfma_f32_16x16x32_bf16(bh, al[kc], acc, 0, 0, 0);
      }
      // lane's candidates: cols m0 + tt*16 + quad*4 + r, all for row gr
      float4 s4 = *(const float4*)&sqm[tt * 16 + quad * 4];  // broadcast read
      const float sv[4] = {s4.x, s4.y, s4.z, s4.w};
      #pragma unroll
      for (int r = 0; r < 4; ++r) {
        float v = 2.f * acc[r] - sr - sv[r];
        int col = m0 + tt * 16 + quad * 4 + r;
        uint64_t key = ((uint64_t)fmono(v) << 32) | (unsigned int)~col;
        topk_ins(key, bk);
      }
    }
  }
  __syncthreads();

  // merge the 4 per-quad lists of each row (scratch aliases sB)
  uint64_t* sk = (uint64_t*)sB;   // 64 rows * 4 quads * 9 * 8B = 18432 B
  #pragma unroll
  for (int j = 0; j < KNN; ++j) sk[((w * 16 + m16) * 4 + quad) * KNN + j] = bk[j];
  __syncthreads();
  if (t < TILE) {
    uint64_t fk[KNN];
    #pragma unroll
    for (int j = 0; j < KNN; ++j) fk[j] = 0ull;
    for (int qq = 0; qq < 4; ++qq)
      #pragma unroll
      for (int j = 0; j < KNN; ++j)
        topk_ins(sk[(t * 4 + qq) * KNN + j], fk);
    size_t base = (((size_t)b * nch + chunk) * NN + r0 + t) * KNN;
    #pragma unroll
    for (int j = 0; j < KNN; ++j) cand_k[base + j] = fk[j];
  }
}

// ---------------------------------------------------------------------------
// K4: merge nch chunk lists -> nn_idx.  4 sub-waves each merge nch/4 chunks,
// sub-wave 0 merges the partials via LDS (u64 keys => merge-tree == serial).
// STANDALONE (r14: fusing this into k_gmax cost +18us -- the 32/8-thread
// merge phases serialized onto every gmax block's critical path).
// ---------------------------------------------------------------------------
__global__ __launch_bounds__(256) void k_nnmerge(const uint64_t* __restrict__ cand_k,
                                                 int* __restrict__ nn_idx, int nch) {
  __shared__ uint64_t sk[64 * 4 * KNN];   // 18432 B
  const int t = threadIdx.x, lane = t & 63, sw = t >> 6;
  const int p = blockIdx.x * 64 + lane;
  const int b = p / NN, n = p % NN;
  const int cpw = nch >> 2;               // chunks per sub-wave (nch 4/8/16)
  uint64_t fk[KNN];
  #pragma unroll
  for (int j = 0; j < KNN; ++j) fk[j] = 0ull;
  for (int ch = sw * cpw; ch < (sw + 1) * cpw; ++ch) {
    size_t base = (((size_t)b * nch + ch) * NN + n) * KNN;
    #pragma unroll
    for (int j = 0; j < KNN; ++j) topk_ins(cand_k[base + j], fk);
  }
  #pragma unroll
  for (int j = 0; j < KNN; ++j) sk[(lane * 4 + sw) * KNN + j] = fk[j];
  __syncthreads();
  if (sw == 0) {
    uint64_t gk[KNN];
    #pragma unroll
    for (int j = 0; j < KNN; ++j) gk[j] = 0ull;
    for (int q = 0; q < 4; ++q)
      #pragma unroll
      for (int j = 0; j < KNN; ++j)
        topk_ins(sk[(lane * 4 + q) * KNN + j], gk);
    #pragma unroll
    for (int j = 0; j < KNN; ++j) {
      int v = (int)(~(unsigned int)gk[j]);
      if ((unsigned)v >= (unsigned)NN) v = 0;  // sentinel guard
      nn_idx[(size_t)p * KNN + j] = v;
    }
  }
}

// ---------------------------------------------------------------------------
// K5: gather-max over linearized gconv.  acc[oc][k] = z[jk] - z[i];
// ymax[p][96+oc] = max_k relu(bn(acc + gb)).  No matmul, no fj staging.
// Coalescing: 32 lanes span 32 consecutive oc -> 128B segments per gather.
// ---------------------------------------------------------------------------
__global__ __launch_bounds__(256) void k_gmax(const float* __restrict__ zbuf,
                                              const int* __restrict__ nn_idx,
                                              const float* __restrict__ gb,
                                              const float* __restrict__ bng,
                                              float* __restrict__ ymax) {
  __shared__ int idxl[PT * KNN];
  const int t = threadIdx.x;
  const int p0 = blockIdx.x * PT;
  const int b0 = p0 / NN;
  if (t < PT * KNN) {
    int v = nn_idx[(size_t)p0 * KNN + t];
    idxl[t] = ((unsigned)v < (unsigned)NN) ? v : 0;
  }
  __syncthreads();
  const int p = t >> 5, l = t & 31;
  const size_t pg = p0 + p;
  const float* zi = zbuf + pg * CC;
  const float* zb = zbuf + (size_t)b0 * NN * CC;
  const float zi0 = zi[l], zi1 = zi[l + 32], zi2 = zi[l + 64];
  const int o0 = 96 + l, o1 = o0 + 32, o2 = o0 + 64;
  const float inv0 = bng[o0] / sqrtf(bng[3 * C2 + o0] + 1e-5f);
  const float inv1 = bng[o1] / sqrtf(bng[3 * C2 + o1] + 1e-5f);
  const float inv2 = bng[o2] / sqrtf(bng[3 * C2 + o2] + 1e-5f);
  const float sh0 = bng[C2 + o0] - bng[2 * C2 + o0] * inv0;
  const float sh1 = bng[C2 + o1] - bng[2 * C2 + o1] * inv1;
  const float sh2 = bng[C2 + o2] - bng[2 * C2 + o2] * inv2;
  const float bs0 = gb[o0], bs1 = gb[o1], bs2 = gb[o2];
  float m0 = 0.f, m1 = 0.f, m2 = 0.f;
  #pragma unroll
  for (int k = 0; k < KNN; ++k) {
    const float* zj = zb + (size_t)idxl[p * KNN + k] * CC;
    float a0 = zj[l]      - zi0;
    float a1 = zj[l + 32] - zi1;
    float a2 = zj[l + 64] - zi2;
    m0 = fmaxf(m0, fmaxf(fmaf(a0 + bs0, inv0, sh0), 0.f));
    m1 = fmaxf(m1, fmaxf(fmaf(a1 + bs1, inv1, sh1), 0.f));
    m2 = fmaxf(m2, fmaxf(fmaf(a2 + bs2, inv2, sh2), 0.f));
  }
  float* orow = ymax + pg * C2 + 96;
  orow[l] = m0; orow[l + 32] = m1; orow[l + 64] = m2;
}

// ---------------------------------------------------------------------------
// K6: out = bn2(fc2_w @ ymax + fc2_b) + x.  512 threads (r13 verified win).
// w2 staged to LDS transposed (r6 win).  LDS = 126 KB.
// ---------------------------------------------------------------------------
__global__ __launch_bounds__(512) void k_fc2(const float* __restrict__ ymax,
                                             const float* __restrict__ w2,
                                             const float* __restrict__ b2,
                                             const float* __restrict__ bn2,
                                             const float* __restrict__ xin,
                                             float* __restrict__ out) {
  __shared__ float ys[64 * 193];       // 49.4 KB
  __shared__ float w2T[C2 * WTS];      // 76.8 KB, w2T[c2*WTS + o]
  const int b = blockIdx.y, n0 = blockIdx.x * 64, t = threadIdx.x;
  for (int i = t; i < 64 * C2; i += 512) {
    int nn = i / C2, c2 = i % C2;
    ys[nn * 193 + c2] = ymax[((size_t)b * NN + n0 + nn) * C2 + c2];
  }
  for (int i = t; i < CC * C2; i += 512) {
    int o = i / C2, c2 = i % C2;       // w2[o][c2] row-major in global
    w2T[c2 * WTS + o] = w2[i];
  }
  __syncthreads();
  const int nn = t & 63;
  const int og = __builtin_amdgcn_readfirstlane(t >> 6);   // 0..7
  float acc[12];
  #pragma unroll
  for (int i = 0; i < 12; ++i) acc[i] = 0.f;
  const float* yrow = ys + nn * 193;
  for (int c2 = 0; c2 < C2; ++c2) {
    float yv = yrow[c2];
    const float* wp = &w2T[c2 * WTS + og * 12];  // 16B-aligned
    float4 w0 = *(const float4*)(wp);
    float4 w1 = *(const float4*)(wp + 4);
    float4 w2v = *(const float4*)(wp + 8);
    const float wv[12] = {w0.x, w0.y, w0.z, w0.w, w1.x, w1.y, w1.z, w1.w,
                          w2v.x, w2v.y, w2v.z, w2v.w};
    #pragma unroll
    for (int oi = 0; oi < 12; ++oi) acc[oi] = fmaf(wv[oi], yv, acc[oi]);
  }
  #pragma unroll
  for (int oi = 0; oi < 12; ++oi) {
    int o = og * 12 + oi;
    float g = bn2[o], be = bn2[CC + o], mn = bn2[2 * CC + o], vr = bn2[3 * CC + o];
    float inv = g / sqrtf(vr + 1e-5f);
    float v = fmaf(acc[oi] + b2[o], inv, be - mn * inv);
    size_t off = ((size_t)b * CC + o) * NN + n0 + nn;
    out[off] = v + xin[off];
  }
}

// ---------------------------------------------------------------------------
extern "C" void kernel_launch(void* const* d_in, const int* in_sizes, int n_in,
                              void* d_out, int out_size, void* d_ws, size_t ws_size,
                              hipStream_t stream) {
  const float* x     = (const float*)d_in[0];
  const float* fc1_w = (const float*)d_in[1];
  const float* fc1_b = (const float*)d_in[2];
  const float* bn1   = (const float*)d_in[3];
  const float* gc_w  = (const float*)d_in[4];
  const float* gc_b  = (const float*)d_in[5];
  const float* bng   = (const float*)d_in[6];
  const float* fc2_w = (const float*)d_in[7];
  const float* fc2_b = (const float*)d_in[8];
  const float* bn2   = (const float*)d_in[9];
  float* out = (float*)d_out;

  const size_t BNC = (size_t)BN_ * NN * CC;
  float* ws = (float*)d_ws;
  float* zbuf = ws;                                   // B*N*96 fp32
  unsigned short* xh = (unsigned short*)(zbuf + BNC); // B*N*C bf16 hi
  unsigned short* xl = xh + BNC;                      // B*N*C bf16 lo
  float* sq     = ws + 2 * BNC;                       // B*N
  float* ymax   = sq + (size_t)BN_ * NN;              // B*N*C2 fp32
  int* nnidx = (int*)(ymax + (size_t)BN_ * NN * C2);

  // cand_k dedicated after nnidx (k_fc1 writes ymax's k-free half before
  // k_dist, so ymax can't host it).  nch ladder 16 -> 8 -> 4 by workspace
  // (nch=4 = 24.72 MB, always within the r0-verified budget).
  const size_t base_bytes =
      (2 * BNC + (size_t)BN_ * NN + (size_t)BN_ * NN * C2) * 4 +
      (size_t)BN_ * NN * KNN * 4;                     // through nnidx
  uint64_t* cand_k = (uint64_t*)((char*)d_ws + base_bytes);
  int nch;
  if (ws_size >= base_bytes + (size_t)BN_ * 16 * NN * KNN * 8)      nch = 16;
  else if (ws_size >= base_bytes + (size_t)BN_ * 8 * NN * KNN * 8)  nch = 8;
  else                                                              nch = 4;

  k_fc1<<<dim3(NN / 64, BN_), 512, 0, stream>>>(x, fc1_w, fc1_b, bn1, gc_w,
                                                gc_b, bng, ymax, zbuf, xh, xl, sq);
  k_dist<<<dim3(NN / TILE, nch, BN_), 256, 0, stream>>>(xh, xl, sq, cand_k);
  k_nnmerge<<<dim3((BN_ * NN) / 64), 256, 0, stream>>>(cand_k, nnidx, nch);
  k_gmax<<<dim3((BN_ * NN) / PT), 256, 0, stream>>>(zbuf, nnidx, gc_b, bng, ymax);
  k_fc2<<<dim3(NN / 64, BN_), 512, 0, stream>>>(ymax, fc2_w, fc2_b, bn2, x, out);
}